// Round 1
// baseline (3282.181 us; speedup 1.0000x reference)
//
#include <hip/hip_runtime.h>

#define USER  100000
#define ITEM  50000
#define NNODE 150000
#define LAT   64
#define TXT   768

// ---------------------------------------------------------------------------
// SpMM (COO, atomic scatter): out[r*64+lane] += scale*vals[e] * x[c*64+lane]
// where x = concat(xu[0:USER], xi[0:ITEM]) indexed by node id c.
// One 64-lane wave per edge; 4 edges per 256-thread block.
// ---------------------------------------------------------------------------
__global__ __launch_bounds__(256) void spmm_kernel(
    const int* __restrict__ rows, const int* __restrict__ cols,
    const float* __restrict__ vals, float scale,
    const float* __restrict__ xu, const float* __restrict__ xi,
    float* __restrict__ out, int nedges)
{
    int e = blockIdx.x * 4 + (threadIdx.x >> 6);
    if (e >= nedges) return;
    int lane = threadIdx.x & 63;
    int r = rows[e];
    int c = cols[e];
    float v = vals[e] * scale;
    const float* x = (c < USER) ? (xu + (size_t)c * LAT)
                                : (xi + (size_t)(c - USER) * LAT);
    atomicAdd(&out[(size_t)r * LAT + lane], v * x[lane]);
}

// ---------------------------------------------------------------------------
// tf[row] = l2_normalize(text[row] @ W + b) ; one wave per item row,
// lane = output column. W (192 KB) stays hot in L2.
// ---------------------------------------------------------------------------
__global__ __launch_bounds__(256) void gemm_norm_kernel(
    const float* __restrict__ text, const float* __restrict__ W,
    const float* __restrict__ b, float* __restrict__ tf, int nitems)
{
    int row = blockIdx.x * 4 + (threadIdx.x >> 6);
    if (row >= nitems) return;
    int lane = threadIdx.x & 63;
    const float4* t4 = (const float4*)(text + (size_t)row * TXT);
    float acc = 0.f;
#pragma unroll 4
    for (int k = 0; k < TXT / 4; ++k) {
        float4 tv = t4[k];
        const float* w = W + (size_t)(k * 4) * LAT + lane;
        acc += tv.x * w[0];
        acc += tv.y * w[LAT];
        acc += tv.z * w[2 * LAT];
        acc += tv.w * w[3 * LAT];
    }
    acc += b[lane];
    // wave-wide sum of squares (row == 64 lanes)
    float ss = acc * acc;
    for (int off = 32; off >= 1; off >>= 1) ss += __shfl_xor(ss, off);
    float nrm = fmaxf(sqrtf(ss), 1e-12f);
    tf[(size_t)row * LAT + lane] = acc / nrm;
}

// A = A + B ; out = A   (A held lambda*ta + e2, B held e1)
__global__ __launch_bounds__(256) void combine_kernel(
    float* __restrict__ A, const float* __restrict__ B,
    float* __restrict__ out, int n4)
{
    int i = blockIdx.x * blockDim.x + threadIdx.x;
    if (i >= n4) return;
    float4 a = ((const float4*)A)[i];
    float4 b = ((const float4*)B)[i];
    a.x += b.x; a.y += b.y; a.z += b.z; a.w += b.w;
    ((float4*)A)[i]   = a;
    ((float4*)out)[i] = a;
}

// out += src
__global__ __launch_bounds__(256) void add_kernel(
    float* __restrict__ out, const float* __restrict__ src, int n4)
{
    int i = blockIdx.x * blockDim.x + threadIdx.x;
    if (i >= n4) return;
    float4 o = ((const float4*)out)[i];
    float4 s = ((const float4*)src)[i];
    o.x += s.x; o.y += s.y; o.z += s.z; o.w += s.w;
    ((float4*)out)[i] = o;
}

extern "C" void kernel_launch(void* const* d_in, const int* in_sizes, int n_in,
                              void* d_out, int out_size, void* d_ws, size_t ws_size,
                              hipStream_t stream)
{
    const float* u        = (const float*)d_in[0];
    const float* it       = (const float*)d_in[1];
    const float* text     = (const float*)d_in[2];
    const float* W        = (const float*)d_in[3];
    const float* b        = (const float*)d_in[4];
    const float* adj_vals = (const float*)d_in[5];
    const float* t_vals   = (const float*)d_in[6];
    const int*   adj_rows = (const int*)d_in[7];
    const int*   adj_cols = (const int*)d_in[8];
    const int*   t_rows   = (const int*)d_in[9];
    const int*   t_cols   = (const int*)d_in[10];
    const int E = in_sizes[5];

    float* out = (float*)d_out;

    // workspace layout: A[N*64] | B[N*64] | tf[ITEM*64]   (~90 MB)
    float* A  = (float*)d_ws;
    float* B  = A + (size_t)NNODE * LAT;
    float* tf = B + (size_t)NNODE * LAT;

    const size_t nbuf = (size_t)NNODE * LAT * sizeof(float);
    hipMemsetAsync(A, 0, nbuf, stream);
    hipMemsetAsync(B, 0, nbuf, stream);

    const int gblk = (ITEM + 3) / 4;
    gemm_norm_kernel<<<gblk, 256, 0, stream>>>(text, W, b, tf, ITEM);

    const int sblk = (E + 3) / 4;
    const int n4   = NNODE * LAT / 4;
    const int eblk = (n4 + 255) / 256;

    // A = lambda * spmm(t, concat(u, i))
    spmm_kernel<<<sblk, 256, 0, stream>>>(t_rows, t_cols, t_vals, 0.2f, u, it, A, E);
    // B = e1 = spmm(adj, concat(u, tf))
    spmm_kernel<<<sblk, 256, 0, stream>>>(adj_rows, adj_cols, adj_vals, 1.0f, u, tf, B, E);
    // A += e2 = spmm(adj, concat(e1[:USER], i))   (e1[:USER] lives in B)
    spmm_kernel<<<sblk, 256, 0, stream>>>(adj_rows, adj_cols, adj_vals, 1.0f, B, it, A, E);
    // A = embeds = A + B ; out = embeds (total layer 0)
    combine_kernel<<<eblk, 256, 0, stream>>>(A, B, out, n4);

    // GNN layer 1: B = spmm(adj, A) ; out += B
    hipMemsetAsync(B, 0, nbuf, stream);
    spmm_kernel<<<sblk, 256, 0, stream>>>(adj_rows, adj_cols, adj_vals, 1.0f,
                                          A, A + (size_t)USER * LAT, B, E);
    add_kernel<<<eblk, 256, 0, stream>>>(out, B, n4);

    // GNN layer 2: A = spmm(adj, B) ; out += A
    hipMemsetAsync(A, 0, nbuf, stream);
    spmm_kernel<<<sblk, 256, 0, stream>>>(adj_rows, adj_cols, adj_vals, 1.0f,
                                          B, B + (size_t)USER * LAT, A, E);
    add_kernel<<<eblk, 256, 0, stream>>>(out, A, n4);
}

// Round 2
// 2062.294 us; speedup vs baseline: 1.5915x; 1.5915x over previous
//
#include <hip/hip_runtime.h>

#define USER  100000
#define ITEM  50000
#define NNODE 150000
#define LAT   64
#define TXT   768
#define RP    150016          // padded rowptr/cnt length (>= NNODE+1, 16B-mult)

// ---------------------------------------------------------------------------
// Atomic-scatter SpMM fallback (used for t-adjacency only if ws is small)
// ---------------------------------------------------------------------------
__global__ __launch_bounds__(256) void spmm_atomic_kernel(
    const int* __restrict__ rows, const int* __restrict__ cols,
    const float* __restrict__ vals, float scale,
    const float* __restrict__ xu, const float* __restrict__ xi,
    float* __restrict__ out, int nedges)
{
    int e = blockIdx.x * 4 + (threadIdx.x >> 6);
    if (e >= nedges) return;
    int lane = threadIdx.x & 63;
    int r = rows[e];
    int c = cols[e];
    float v = vals[e] * scale;
    const float* x = (c < USER) ? (xu + (size_t)c * LAT)
                                : (xi + (size_t)(c - USER) * LAT);
    atomicAdd(&out[(size_t)r * LAT + lane], v * x[lane]);
}

// ---------------------------------------------------------------------------
// tf = l2_normalize(text @ W + b).  32 rows/block, 8 rows/thread, lane = col.
// W traffic: 192KB per block (L2-hot), text streamed once.
// ---------------------------------------------------------------------------
__global__ __launch_bounds__(256) void gemm_norm_kernel(
    const float* __restrict__ text, const float* __restrict__ W,
    const float* __restrict__ b, float* __restrict__ tf, int nitems)
{
    int wave = threadIdx.x >> 6;
    int lane = threadIdx.x & 63;
    int row0 = blockIdx.x * 32 + wave * 8;

    // clamped per-row base pointers (avoid OOB reads in tail block)
    const float4* t4[8];
#pragma unroll
    for (int r = 0; r < 8; ++r) {
        int rr = row0 + r;
        if (rr >= nitems) rr = nitems - 1;
        t4[r] = (const float4*)(text + (size_t)rr * TXT);
    }
    const float* wp = W + lane;

    float acc[8] = {0.f, 0.f, 0.f, 0.f, 0.f, 0.f, 0.f, 0.f};
    for (int k4 = 0; k4 < TXT / 4; ++k4) {
        int k = k4 * 4;
        float w0 = wp[(size_t)(k + 0) * LAT];
        float w1 = wp[(size_t)(k + 1) * LAT];
        float w2 = wp[(size_t)(k + 2) * LAT];
        float w3 = wp[(size_t)(k + 3) * LAT];
#pragma unroll
        for (int r = 0; r < 8; ++r) {
            float4 tv = t4[r][k4];
            acc[r] = fmaf(tv.x, w0, acc[r]);
            acc[r] = fmaf(tv.y, w1, acc[r]);
            acc[r] = fmaf(tv.z, w2, acc[r]);
            acc[r] = fmaf(tv.w, w3, acc[r]);
        }
    }
    float bias = b[lane];
#pragma unroll
    for (int r = 0; r < 8; ++r) {
        float v = acc[r] + bias;
        float ss = v * v;
        for (int off = 32; off >= 1; off >>= 1) ss += __shfl_xor(ss, off);
        float nrm = fmaxf(sqrtf(ss), 1e-12f);
        if (row0 + r < nitems) tf[(size_t)(row0 + r) * LAT + lane] = v / nrm;
    }
}

// ---------------------------------------------------------------------------
// CSR build: histogram -> 3-kernel exclusive scan -> scatter
// ---------------------------------------------------------------------------
__global__ __launch_bounds__(256) void hist_kernel(
    const int* __restrict__ rows, int* __restrict__ cnt, int n)
{
    int i = blockIdx.x * 256 + threadIdx.x;
    if (i < n) atomicAdd(&cnt[rows[i]], 1);
}

__global__ __launch_bounds__(256) void scan1_kernel(
    const int* __restrict__ cnt, int* __restrict__ rowptr,
    int* __restrict__ bsum, int n)
{
    __shared__ int s[256];
    int i = blockIdx.x * 256 + threadIdx.x;
    int v = (i < n) ? cnt[i] : 0;
    s[threadIdx.x] = v;
    __syncthreads();
    for (int off = 1; off < 256; off <<= 1) {
        int t = (threadIdx.x >= off) ? s[threadIdx.x - off] : 0;
        __syncthreads();
        s[threadIdx.x] += t;
        __syncthreads();
    }
    if (i < n) rowptr[i + 1] = s[threadIdx.x];   // inclusive within chunk
    if (threadIdx.x == 255) bsum[blockIdx.x] = s[255];
}

__global__ __launch_bounds__(1024) void scan2_kernel(int* __restrict__ bsum, int nb)
{
    __shared__ int s[1024];
    int t = threadIdx.x;
    int v = (t < nb) ? bsum[t] : 0;
    s[t] = v;
    __syncthreads();
    for (int off = 1; off < 1024; off <<= 1) {
        int u = (t >= off) ? s[t - off] : 0;
        __syncthreads();
        s[t] += u;
        __syncthreads();
    }
    if (t < nb) bsum[t] = s[t] - v;              // exclusive
}

__global__ __launch_bounds__(256) void scan3_kernel(
    int* __restrict__ rowptr, const int* __restrict__ bsum, int n)
{
    int i = blockIdx.x * 256 + threadIdx.x;
    if (i < n) rowptr[i + 1] += bsum[i >> 8];
    if (i == 0) rowptr[0] = 0;
}

__global__ __launch_bounds__(256) void scatter_kernel(
    const int* __restrict__ rows, const int* __restrict__ cols,
    const float* __restrict__ vals, const int* __restrict__ rowptr,
    int* __restrict__ fill, int* __restrict__ ccol, float* __restrict__ cval,
    int n)
{
    int e = blockIdx.x * 256 + threadIdx.x;
    if (e >= n) return;
    int r = rows[e];
    int pos = rowptr[r] + atomicAdd(&fill[r], 1);
    ccol[pos] = cols[e];
    cval[pos] = vals[e];
}

// ---------------------------------------------------------------------------
// CSR gather SpMM: out[r] = scale * sum_e val*x[col]  (+ addsrc[r] if given)
//                  out2[r] += same  (if given).  One wave per row.
// ---------------------------------------------------------------------------
__global__ __launch_bounds__(256) void spmm_csr_kernel(
    const int* __restrict__ rowptr, const int* __restrict__ ccol,
    const float* __restrict__ cval,
    const float* __restrict__ xu, const float* __restrict__ xi,
    float scale, const float* __restrict__ addsrc,
    float* __restrict__ out, float* __restrict__ out2, int n)
{
    int r = blockIdx.x * 4 + (threadIdx.x >> 6);
    if (r >= n) return;
    int lane = threadIdx.x & 63;
    int start = rowptr[r], end = rowptr[r + 1];
    float acc = 0.f;
    for (int e = start; e < end; ++e) {
        int c = __builtin_amdgcn_readfirstlane(ccol[e]);
        float v = cval[e];
        const float* x = (c < USER) ? (xu + (size_t)c * LAT)
                                    : (xi + (size_t)(c - USER) * LAT);
        acc = fmaf(v, x[lane], acc);
    }
    size_t idx = (size_t)r * LAT + lane;
    float res = scale * acc + (addsrc ? addsrc[idx] : 0.f);
    out[idx] = res;
    if (out2) out2[idx] += res;
}

// A = A + B ; out = A
__global__ __launch_bounds__(256) void combine_kernel(
    float* __restrict__ A, const float* __restrict__ B,
    float* __restrict__ out, int n4)
{
    int i = blockIdx.x * blockDim.x + threadIdx.x;
    if (i >= n4) return;
    float4 a = ((const float4*)A)[i];
    float4 b = ((const float4*)B)[i];
    a.x += b.x; a.y += b.y; a.z += b.z; a.w += b.w;
    ((float4*)A)[i]   = a;
    ((float4*)out)[i] = a;
}

// ---------------------------------------------------------------------------
extern "C" void kernel_launch(void* const* d_in, const int* in_sizes, int n_in,
                              void* d_out, int out_size, void* d_ws, size_t ws_size,
                              hipStream_t stream)
{
    const float* u        = (const float*)d_in[0];
    const float* it       = (const float*)d_in[1];
    const float* text     = (const float*)d_in[2];
    const float* W        = (const float*)d_in[3];
    const float* b        = (const float*)d_in[4];
    const float* adj_vals = (const float*)d_in[5];
    const float* t_vals   = (const float*)d_in[6];
    const int*   adj_rows = (const int*)d_in[7];
    const int*   adj_cols = (const int*)d_in[8];
    const int*   t_rows   = (const int*)d_in[9];
    const int*   t_cols   = (const int*)d_in[10];
    const int E = in_sizes[5];

    float* out = (float*)d_out;

    // ---- workspace carve ----
    char* p = (char*)d_ws;
    size_t used = 0;
    auto carve = [&](size_t bytes) {
        char* q = p + used;
        used += (bytes + 255) & ~(size_t)255;
        return q;
    };
    float* A   = (float*)carve((size_t)NNODE * LAT * 4);
    float* B   = (float*)carve((size_t)NNODE * LAT * 4);
    float* tf  = (float*)carve((size_t)ITEM * LAT * 4);
    int*   ap  = (int*)  carve((size_t)RP * 4);        // adj rowptr
    int*   acl = (int*)  carve((size_t)E * 4);         // adj csr cols
    float* avl = (float*)carve((size_t)E * 4);         // adj csr vals
    int*   cnt = (int*)  carve((size_t)RP * 4);
    int*   fil = (int*)  carve((size_t)RP * 4);
    int*   bs  = (int*)  carve(4096);
    size_t base_used = used;
    int*   tp  = (int*)  carve((size_t)RP * 4);        // t rowptr
    int*   tcl = (int*)  carve((size_t)E * 4);
    float* tvl = (float*)carve((size_t)E * 4);
    bool t_csr = (used <= ws_size);

    const int eblk  = (E + 255) / 256;                 // per-edge kernels
    const int nblk  = (NNODE + 255) / 256;
    const int nb    = (NNODE + 255) / 256;             // scan chunks (586)
    const int sblk  = (NNODE + 3) / 4;                 // spmm: 4 rows/block
    const int n4    = NNODE * LAT / 4;
    const int cblk  = (n4 + 255) / 256;
    const int gblk  = (ITEM + 31) / 32;

    // ---- GEMM + normalize ----
    gemm_norm_kernel<<<gblk, 256, 0, stream>>>(text, W, b, tf, ITEM);

    // ---- build adj CSR ----
    hipMemsetAsync(cnt, 0, (size_t)RP * 4, stream);
    hist_kernel<<<eblk, 256, 0, stream>>>(adj_rows, cnt, E);
    scan1_kernel<<<nb, 256, 0, stream>>>(cnt, ap, bs, NNODE);
    scan2_kernel<<<1, 1024, 0, stream>>>(bs, nb);
    scan3_kernel<<<nblk, 256, 0, stream>>>(ap, bs, NNODE);
    hipMemsetAsync(fil, 0, (size_t)RP * 4, stream);
    scatter_kernel<<<eblk, 256, 0, stream>>>(adj_rows, adj_cols, adj_vals,
                                             ap, fil, acl, avl, E);

    // ---- A = 0.2 * spmm(t, concat(u, i)) ----
    if (t_csr) {
        hipMemsetAsync(cnt, 0, (size_t)RP * 4, stream);
        hist_kernel<<<eblk, 256, 0, stream>>>(t_rows, cnt, E);
        scan1_kernel<<<nb, 256, 0, stream>>>(cnt, tp, bs, NNODE);
        scan2_kernel<<<1, 1024, 0, stream>>>(bs, nb);
        scan3_kernel<<<nblk, 256, 0, stream>>>(tp, bs, NNODE);
        hipMemsetAsync(fil, 0, (size_t)RP * 4, stream);
        scatter_kernel<<<eblk, 256, 0, stream>>>(t_rows, t_cols, t_vals,
                                                 tp, fil, tcl, tvl, E);
        spmm_csr_kernel<<<sblk, 256, 0, stream>>>(tp, tcl, tvl, u, it, 0.2f,
                                                  nullptr, A, nullptr, NNODE);
    } else {
        hipMemsetAsync(A, 0, (size_t)NNODE * LAT * 4, stream);
        spmm_atomic_kernel<<<(E + 3) / 4, 256, 0, stream>>>(
            t_rows, t_cols, t_vals, 0.2f, u, it, A, E);
    }

    // ---- B = e1 = spmm(adj, concat(u, tf)) ----
    spmm_csr_kernel<<<sblk, 256, 0, stream>>>(ap, acl, avl, u, tf, 1.0f,
                                              nullptr, B, nullptr, NNODE);
    // ---- A = A + e2 = A + spmm(adj, concat(e1_u, i)) ----
    spmm_csr_kernel<<<sblk, 256, 0, stream>>>(ap, acl, avl, B, it, 1.0f,
                                              A, A, nullptr, NNODE);
    // ---- A = embeds = A + B ; out = A ----
    combine_kernel<<<cblk, 256, 0, stream>>>(A, B, out, n4);
    // ---- layer 1: B = spmm(adj, A) ; out += B ----
    spmm_csr_kernel<<<sblk, 256, 0, stream>>>(ap, acl, avl,
                                              A, A + (size_t)USER * LAT, 1.0f,
                                              nullptr, B, out, NNODE);
    // ---- layer 2: A = spmm(adj, B) ; out += A ----
    spmm_csr_kernel<<<sblk, 256, 0, stream>>>(ap, acl, avl,
                                              B, B + (size_t)USER * LAT, 1.0f,
                                              nullptr, A, out, NNODE);
}

// Round 3
// 1171.643 us; speedup vs baseline: 2.8013x; 1.7602x over previous
//
#include <hip/hip_runtime.h>

#define USER  100000
#define ITEM  50000
#define NNODE 150000
#define LAT   64
#define TXT   768
#define RP    150016          // padded rowptr/cnt length (>= NNODE+1)

// ---------------------------------------------------------------------------
// Atomic-scatter SpMM fallback (used for t-adjacency only if ws is small)
// ---------------------------------------------------------------------------
__global__ __launch_bounds__(256) void spmm_atomic_kernel(
    const int* __restrict__ rows, const int* __restrict__ cols,
    const float* __restrict__ vals, float scale,
    const float* __restrict__ xu, const float* __restrict__ xi,
    float* __restrict__ out, int nedges)
{
    int e = blockIdx.x * 4 + (threadIdx.x >> 6);
    if (e >= nedges) return;
    int lane = threadIdx.x & 63;
    int r = rows[e];
    int c = cols[e];
    float v = vals[e] * scale;
    const float* x = (c < USER) ? (xu + (size_t)c * LAT)
                                : (xi + (size_t)(c - USER) * LAT);
    atomicAdd(&out[(size_t)r * LAT + lane], v * x[lane]);
}

// ---------------------------------------------------------------------------
// LDS-tiled GEMM + row L2-normalize:  tf = l2norm(text @ W + b)
// 64x64 tile, BK=32, 256 threads, 4x4 outputs per thread.
// As stored k-major [BK][68] (pad => aligned, conflict-free b128 reads).
// ---------------------------------------------------------------------------
__global__ __launch_bounds__(256) void gemm_norm_kernel(
    const float* __restrict__ text, const float* __restrict__ W,
    const float* __restrict__ b, float* __restrict__ tf, int nitems)
{
    __shared__ float As[32][68];     // [k][row]
    __shared__ float Bs[32][64];     // [k][col]

    const int tid = threadIdx.x;
    const int tx  = tid & 15;        // col group: cols tx*4..tx*4+3
    const int ty  = tid >> 4;        // row group: rows ty*4..ty*4+3  (0..15)
    const int row0 = blockIdx.x * 64;

    float acc[4][4] = {};

    const int lrow = tid >> 3;             // 0..31 (A-tile loader)
    const int lk4  = (tid & 7) * 4;        // k offset 0,4,...,28

    for (int k0 = 0; k0 < TXT; k0 += 32) {
        // ---- stage A tile (64 rows x 32 k), transposed to k-major ----
#pragma unroll
        for (int half = 0; half < 2; ++half) {
            int r = lrow + half * 32;
            int gr = row0 + r;
            if (gr >= nitems) gr = nitems - 1;          // clamp (tail block)
            float4 tv = *(const float4*)(text + (size_t)gr * TXT + k0 + lk4);
            As[lk4 + 0][r] = tv.x;
            As[lk4 + 1][r] = tv.y;
            As[lk4 + 2][r] = tv.z;
            As[lk4 + 3][r] = tv.w;
        }
        // ---- stage B tile (32 k x 64 cols) — contiguous 8KB ----
        const float4* wf = (const float4*)(W + (size_t)k0 * LAT);
        ((float4*)Bs)[tid]       = wf[tid];
        ((float4*)Bs)[tid + 256] = wf[tid + 256];
        __syncthreads();

        // ---- compute ----
#pragma unroll
        for (int k = 0; k < 32; ++k) {
            float4 a4 = *(const float4*)&As[k][ty * 4];
            float4 b4 = *(const float4*)&Bs[k][tx * 4];
            float av[4] = {a4.x, a4.y, a4.z, a4.w};
            float bv[4] = {b4.x, b4.y, b4.z, b4.w};
#pragma unroll
            for (int i = 0; i < 4; ++i)
#pragma unroll
                for (int j = 0; j < 4; ++j)
                    acc[i][j] = fmaf(av[i], bv[j], acc[i][j]);
        }
        __syncthreads();
    }

    // ---- bias + per-row l2 norm (row spans 16 lanes with same ty) ----
    float4 b4 = *(const float4*)(b + tx * 4);
    float bv[4] = {b4.x, b4.y, b4.z, b4.w};
#pragma unroll
    for (int i = 0; i < 4; ++i) {
        float v[4];
        float ss = 0.f;
#pragma unroll
        for (int j = 0; j < 4; ++j) {
            v[j] = acc[i][j] + bv[j];
            ss = fmaf(v[j], v[j], ss);
        }
        ss += __shfl_xor(ss, 1);
        ss += __shfl_xor(ss, 2);
        ss += __shfl_xor(ss, 4);
        ss += __shfl_xor(ss, 8);
        float inv = 1.0f / fmaxf(sqrtf(ss), 1e-12f);
        int gr = row0 + ty * 4 + i;
        if (gr < nitems) {
            float4 o = {v[0] * inv, v[1] * inv, v[2] * inv, v[3] * inv};
            *(float4*)(tf + (size_t)gr * LAT + tx * 4) = o;
        }
    }
}

// ---------------------------------------------------------------------------
// CSR build: histogram -> 3-kernel exclusive scan -> scatter
// ---------------------------------------------------------------------------
__global__ __launch_bounds__(256) void hist_kernel(
    const int* __restrict__ rows, int* __restrict__ cnt, int n)
{
    int i = blockIdx.x * 256 + threadIdx.x;
    if (i < n) atomicAdd(&cnt[rows[i]], 1);
}

__global__ __launch_bounds__(256) void scan1_kernel(
    const int* __restrict__ cnt, int* __restrict__ rowptr,
    int* __restrict__ bsum, int n)
{
    __shared__ int s[256];
    int i = blockIdx.x * 256 + threadIdx.x;
    int v = (i < n) ? cnt[i] : 0;
    s[threadIdx.x] = v;
    __syncthreads();
    for (int off = 1; off < 256; off <<= 1) {
        int t = (threadIdx.x >= off) ? s[threadIdx.x - off] : 0;
        __syncthreads();
        s[threadIdx.x] += t;
        __syncthreads();
    }
    if (i < n) rowptr[i + 1] = s[threadIdx.x];
    if (threadIdx.x == 255) bsum[blockIdx.x] = s[255];
}

__global__ __launch_bounds__(1024) void scan2_kernel(int* __restrict__ bsum, int nb)
{
    __shared__ int s[1024];
    int t = threadIdx.x;
    int v = (t < nb) ? bsum[t] : 0;
    s[t] = v;
    __syncthreads();
    for (int off = 1; off < 1024; off <<= 1) {
        int u = (t >= off) ? s[t - off] : 0;
        __syncthreads();
        s[t] += u;
        __syncthreads();
    }
    if (t < nb) bsum[t] = s[t] - v;              // exclusive
}

__global__ __launch_bounds__(256) void scan3_kernel(
    int* __restrict__ rowptr, const int* __restrict__ bsum, int n)
{
    int i = blockIdx.x * 256 + threadIdx.x;
    if (i < n) rowptr[i + 1] += bsum[i >> 8];
    if (i == 0) rowptr[0] = 0;
}

__global__ __launch_bounds__(256) void scatter_kernel(
    const int* __restrict__ rows, const int* __restrict__ cols,
    const float* __restrict__ vals, const int* __restrict__ rowptr,
    int* __restrict__ fill, int* __restrict__ ccol, float* __restrict__ cval,
    int n)
{
    int e = blockIdx.x * 256 + threadIdx.x;
    if (e >= n) return;
    int r = rows[e];
    int pos = rowptr[r] + atomicAdd(&fill[r], 1);
    ccol[pos] = cols[e];
    cval[pos] = vals[e];
}

// ---------------------------------------------------------------------------
// CSR gather SpMM, 4 edge-groups x 16 lanes x float4 per wave (one row/wave):
//   out[r] = scale * sum_e val*x[col]  (+ addsrc[r])  ;  out2[r] += same
// ---------------------------------------------------------------------------
__global__ __launch_bounds__(256) void spmm_csr_kernel(
    const int* __restrict__ rowptr, const int* __restrict__ ccol,
    const float* __restrict__ cval,
    const float* __restrict__ xu, const float* __restrict__ xi,
    float scale, const float* __restrict__ addsrc,
    float* __restrict__ out, float* __restrict__ out2, int n)
{
    int r = blockIdx.x * 4 + (threadIdx.x >> 6);
    if (r >= n) return;
    int lane = threadIdx.x & 63;
    int g = lane >> 4;          // edge group 0..3
    int l = lane & 15;          // feature chunk: floats 4l..4l+3

    int start = rowptr[r], end = rowptr[r + 1];
    float4 acc = {0.f, 0.f, 0.f, 0.f};
    for (int e = start + g; e < end; e += 4) {
        int c = ccol[e];
        float v = cval[e];
        const float* x = (c < USER) ? (xu + (size_t)c * LAT)
                                    : (xi + (size_t)(c - USER) * LAT);
        float4 xv = *(const float4*)(x + 4 * l);
        acc.x = fmaf(v, xv.x, acc.x);
        acc.y = fmaf(v, xv.y, acc.y);
        acc.z = fmaf(v, xv.z, acc.z);
        acc.w = fmaf(v, xv.w, acc.w);
    }
    // reduce the 4 edge groups
#pragma unroll
    for (int off = 16; off <= 32; off <<= 1) {
        acc.x += __shfl_xor(acc.x, off);
        acc.y += __shfl_xor(acc.y, off);
        acc.z += __shfl_xor(acc.z, off);
        acc.w += __shfl_xor(acc.w, off);
    }
    if (g == 0) {
        size_t idx = (size_t)r * LAT + 4 * l;
        float4 res = {scale * acc.x, scale * acc.y, scale * acc.z, scale * acc.w};
        if (addsrc) {
            float4 a = *(const float4*)(addsrc + idx);
            res.x += a.x; res.y += a.y; res.z += a.z; res.w += a.w;
        }
        *(float4*)(out + idx) = res;
        if (out2) {
            float4 o = *(const float4*)(out2 + idx);
            o.x += res.x; o.y += res.y; o.z += res.z; o.w += res.w;
            *(float4*)(out2 + idx) = o;
        }
    }
}

// A = A + B ; out = A
__global__ __launch_bounds__(256) void combine_kernel(
    float* __restrict__ A, const float* __restrict__ B,
    float* __restrict__ out, int n4)
{
    int i = blockIdx.x * blockDim.x + threadIdx.x;
    if (i >= n4) return;
    float4 a = ((const float4*)A)[i];
    float4 b = ((const float4*)B)[i];
    a.x += b.x; a.y += b.y; a.z += b.z; a.w += b.w;
    ((float4*)A)[i]   = a;
    ((float4*)out)[i] = a;
}

// ---------------------------------------------------------------------------
extern "C" void kernel_launch(void* const* d_in, const int* in_sizes, int n_in,
                              void* d_out, int out_size, void* d_ws, size_t ws_size,
                              hipStream_t stream)
{
    const float* u        = (const float*)d_in[0];
    const float* it       = (const float*)d_in[1];
    const float* text     = (const float*)d_in[2];
    const float* W        = (const float*)d_in[3];
    const float* b        = (const float*)d_in[4];
    const float* adj_vals = (const float*)d_in[5];
    const float* t_vals   = (const float*)d_in[6];
    const int*   adj_rows = (const int*)d_in[7];
    const int*   adj_cols = (const int*)d_in[8];
    const int*   t_rows   = (const int*)d_in[9];
    const int*   t_cols   = (const int*)d_in[10];
    const int E = in_sizes[5];

    float* out = (float*)d_out;

    // ---- workspace carve ----
    char* p = (char*)d_ws;
    size_t used = 0;
    auto carve = [&](size_t bytes) {
        char* q = p + used;
        used += (bytes + 255) & ~(size_t)255;
        return q;
    };
    float* A   = (float*)carve((size_t)NNODE * LAT * 4);
    float* B   = (float*)carve((size_t)NNODE * LAT * 4);
    float* tf  = (float*)carve((size_t)ITEM * LAT * 4);
    int*   ap  = (int*)  carve((size_t)RP * 4);        // adj rowptr
    int*   acl = (int*)  carve((size_t)E * 4);         // adj csr cols
    float* avl = (float*)carve((size_t)E * 4);         // adj csr vals
    int*   cnt = (int*)  carve((size_t)RP * 4);
    int*   fil = (int*)  carve((size_t)RP * 4);
    int*   bs  = (int*)  carve(4096);
    int*   tp  = (int*)  carve((size_t)RP * 4);        // t rowptr
    int*   tcl = (int*)  carve((size_t)E * 4);
    float* tvl = (float*)carve((size_t)E * 4);
    bool t_csr = (used <= ws_size);

    const int eblk  = (E + 255) / 256;
    const int nblk  = (NNODE + 255) / 256;
    const int nb    = (NNODE + 255) / 256;             // scan chunks (586)
    const int sblk  = (NNODE + 3) / 4;
    const int n4    = NNODE * LAT / 4;
    const int cblk  = (n4 + 255) / 256;
    const int gblk  = (ITEM + 63) / 64;

    // ---- GEMM + normalize ----
    gemm_norm_kernel<<<gblk, 256, 0, stream>>>(text, W, b, tf, ITEM);

    // ---- build adj CSR ----
    hipMemsetAsync(cnt, 0, (size_t)RP * 4, stream);
    hist_kernel<<<eblk, 256, 0, stream>>>(adj_rows, cnt, E);
    scan1_kernel<<<nb, 256, 0, stream>>>(cnt, ap, bs, NNODE);
    scan2_kernel<<<1, 1024, 0, stream>>>(bs, nb);
    scan3_kernel<<<nblk, 256, 0, stream>>>(ap, bs, NNODE);
    hipMemsetAsync(fil, 0, (size_t)RP * 4, stream);
    scatter_kernel<<<eblk, 256, 0, stream>>>(adj_rows, adj_cols, adj_vals,
                                             ap, fil, acl, avl, E);

    // ---- A = 0.2 * spmm(t, concat(u, i)) ----
    if (t_csr) {
        hipMemsetAsync(cnt, 0, (size_t)RP * 4, stream);
        hist_kernel<<<eblk, 256, 0, stream>>>(t_rows, cnt, E);
        scan1_kernel<<<nb, 256, 0, stream>>>(cnt, tp, bs, NNODE);
        scan2_kernel<<<1, 1024, 0, stream>>>(bs, nb);
        scan3_kernel<<<nblk, 256, 0, stream>>>(tp, bs, NNODE);
        hipMemsetAsync(fil, 0, (size_t)RP * 4, stream);
        scatter_kernel<<<eblk, 256, 0, stream>>>(t_rows, t_cols, t_vals,
                                                 tp, fil, tcl, tvl, E);
        spmm_csr_kernel<<<sblk, 256, 0, stream>>>(tp, tcl, tvl, u, it, 0.2f,
                                                  nullptr, A, nullptr, NNODE);
    } else {
        hipMemsetAsync(A, 0, (size_t)NNODE * LAT * 4, stream);
        spmm_atomic_kernel<<<(E + 3) / 4, 256, 0, stream>>>(
            t_rows, t_cols, t_vals, 0.2f, u, it, A, E);
    }

    // ---- B = e1 = spmm(adj, concat(u, tf)) ----
    spmm_csr_kernel<<<sblk, 256, 0, stream>>>(ap, acl, avl, u, tf, 1.0f,
                                              nullptr, B, nullptr, NNODE);
    // ---- A = A + e2 = A + spmm(adj, concat(e1_u, i)) ----
    spmm_csr_kernel<<<sblk, 256, 0, stream>>>(ap, acl, avl, B, it, 1.0f,
                                              A, A, nullptr, NNODE);
    // ---- A = embeds = A + B ; out = A ----
    combine_kernel<<<cblk, 256, 0, stream>>>(A, B, out, n4);
    // ---- layer 1: B = spmm(adj, A) ; out += B ----
    spmm_csr_kernel<<<sblk, 256, 0, stream>>>(ap, acl, avl,
                                              A, A + (size_t)USER * LAT, 1.0f,
                                              nullptr, B, out, NNODE);
    // ---- layer 2: A = spmm(adj, B) ; out += A ----
    spmm_csr_kernel<<<sblk, 256, 0, stream>>>(ap, acl, avl,
                                              B, B + (size_t)USER * LAT, 1.0f,
                                              nullptr, A, out, NNODE);
}

// Round 4
// 1112.337 us; speedup vs baseline: 2.9507x; 1.0533x over previous
//
#include <hip/hip_runtime.h>

#define USER  100000
#define ITEM  50000
#define NNODE 150000
#define LAT   64
#define TXT   768
#define RP    150016          // padded rowptr/cnt length (>= NNODE+1, 256B-mult elems)

typedef unsigned long long u64;

// ---------------------------------------------------------------------------
// Atomic-scatter SpMM fallback (t-adjacency only, if ws is too small for 2 CSRs)
// ---------------------------------------------------------------------------
__global__ __launch_bounds__(256) void spmm_atomic_kernel(
    const int* __restrict__ rows, const int* __restrict__ cols,
    const float* __restrict__ vals, float scale,
    const float* __restrict__ xu, const float* __restrict__ xi,
    float* __restrict__ out, int nedges)
{
    int e = blockIdx.x * 4 + (threadIdx.x >> 6);
    if (e >= nedges) return;
    int lane = threadIdx.x & 63;
    int r = rows[e];
    int c = cols[e];
    float v = vals[e] * scale;
    const float* x = (c < USER) ? (xu + (size_t)c * LAT)
                                : (xi + (size_t)(c - USER) * LAT);
    atomicAdd(&out[(size_t)r * LAT + lane], v * x[lane]);
}

// ---------------------------------------------------------------------------
// LDS-tiled GEMM + row L2-normalize:  tf = l2norm(text @ W + b)
// 64x64 tile, BK=32, 256 threads, 4x4 outputs per thread.
// ---------------------------------------------------------------------------
__global__ __launch_bounds__(256) void gemm_norm_kernel(
    const float* __restrict__ text, const float* __restrict__ W,
    const float* __restrict__ b, float* __restrict__ tf, int nitems)
{
    __shared__ float As[32][68];     // [k][row], pad 68 => conflict-free b128
    __shared__ float Bs[32][64];     // [k][col]

    const int tid = threadIdx.x;
    const int tx  = tid & 15;
    const int ty  = tid >> 4;
    const int row0 = blockIdx.x * 64;

    float acc[4][4] = {};

    const int lrow = tid >> 3;             // 0..31
    const int lk4  = (tid & 7) * 4;        // 0,4,...,28

    for (int k0 = 0; k0 < TXT; k0 += 32) {
#pragma unroll
        for (int half = 0; half < 2; ++half) {
            int r = lrow + half * 32;
            int gr = row0 + r;
            if (gr >= nitems) gr = nitems - 1;
            float4 tv = *(const float4*)(text + (size_t)gr * TXT + k0 + lk4);
            As[lk4 + 0][r] = tv.x;
            As[lk4 + 1][r] = tv.y;
            As[lk4 + 2][r] = tv.z;
            As[lk4 + 3][r] = tv.w;
        }
        const float4* wf = (const float4*)(W + (size_t)k0 * LAT);
        ((float4*)Bs)[tid]       = wf[tid];
        ((float4*)Bs)[tid + 256] = wf[tid + 256];
        __syncthreads();

#pragma unroll
        for (int k = 0; k < 32; ++k) {
            float4 a4 = *(const float4*)&As[k][ty * 4];
            float4 b4 = *(const float4*)&Bs[k][tx * 4];
            float av[4] = {a4.x, a4.y, a4.z, a4.w};
            float bv[4] = {b4.x, b4.y, b4.z, b4.w};
#pragma unroll
            for (int i = 0; i < 4; ++i)
#pragma unroll
                for (int j = 0; j < 4; ++j)
                    acc[i][j] = fmaf(av[i], bv[j], acc[i][j]);
        }
        __syncthreads();
    }

    float4 b4 = *(const float4*)(b + tx * 4);
    float bv[4] = {b4.x, b4.y, b4.z, b4.w};
#pragma unroll
    for (int i = 0; i < 4; ++i) {
        float v[4];
        float ss = 0.f;
#pragma unroll
        for (int j = 0; j < 4; ++j) {
            v[j] = acc[i][j] + bv[j];
            ss = fmaf(v[j], v[j], ss);
        }
        ss += __shfl_xor(ss, 1);
        ss += __shfl_xor(ss, 2);
        ss += __shfl_xor(ss, 4);
        ss += __shfl_xor(ss, 8);
        float inv = 1.0f / fmaxf(sqrtf(ss), 1e-12f);
        int gr = row0 + ty * 4 + i;
        if (gr < nitems) {
            float4 o = {v[0] * inv, v[1] * inv, v[2] * inv, v[3] * inv};
            *(float4*)(tf + (size_t)gr * LAT + tx * 4) = o;
        }
    }
}

// ---------------------------------------------------------------------------
// CSR build (both matrices in one pass each stage)
// ---------------------------------------------------------------------------
__global__ __launch_bounds__(256) void hist_both_kernel(
    const int* __restrict__ arows, int* __restrict__ cntA,
    const int* __restrict__ trows, int* __restrict__ cntT, int n)
{
    int i = blockIdx.x * 256 + threadIdx.x;
    if (i >= n) return;
    atomicAdd(&cntA[arows[i]], 1);
    if (cntT) atomicAdd(&cntT[trows[i]], 1);
}

// inclusive scan per 256-chunk; blockIdx.y selects matrix
__global__ __launch_bounds__(256) void scan1_kernel(
    const int* __restrict__ cntA, int* __restrict__ rpA,
    const int* __restrict__ cntT, int* __restrict__ rpT,
    int* __restrict__ bsum, int nb, int n)
{
    const int* cnt = blockIdx.y ? cntT : cntA;
    int*       rp  = blockIdx.y ? rpT  : rpA;
    __shared__ int s[256];
    int i = blockIdx.x * 256 + threadIdx.x;
    int v = (i < n) ? cnt[i] : 0;
    s[threadIdx.x] = v;
    __syncthreads();
    for (int off = 1; off < 256; off <<= 1) {
        int t = (threadIdx.x >= off) ? s[threadIdx.x - off] : 0;
        __syncthreads();
        s[threadIdx.x] += t;
        __syncthreads();
    }
    if (i < n) rp[i + 1] = s[threadIdx.x];
    if (threadIdx.x == 255) bsum[blockIdx.y * nb + blockIdx.x] = s[255];
}

// exclusive scan of each matrix's chunk sums; blockIdx.x selects matrix
__global__ __launch_bounds__(1024) void scan2_kernel(int* __restrict__ bsum, int nb)
{
    int* bs = bsum + blockIdx.x * nb;
    __shared__ int s[1024];
    int t = threadIdx.x;
    int v = (t < nb) ? bs[t] : 0;
    s[t] = v;
    __syncthreads();
    for (int off = 1; off < 1024; off <<= 1) {
        int u = (t >= off) ? s[t - off] : 0;
        __syncthreads();
        s[t] += u;
        __syncthreads();
    }
    if (t < nb) bs[t] = s[t] - v;
}

// add chunk offsets; also emit fill-cursor copy (fil[r] = rowptr[r])
__global__ __launch_bounds__(256) void scan3_kernel(
    int* __restrict__ rpA, int* __restrict__ filA,
    int* __restrict__ rpT, int* __restrict__ filT,
    const int* __restrict__ bsum, int nb, int n)
{
    int*       rp  = blockIdx.y ? rpT  : rpA;
    int*       fil = blockIdx.y ? filT : filA;
    const int* bs  = bsum + blockIdx.y * nb;
    int i = blockIdx.x * 256 + threadIdx.x;
    if (i < n) {
        int v = rp[i + 1] + bs[i >> 8];
        rp[i + 1] = v;
        if (i + 1 < n) fil[i + 1] = v;
    }
    if (i == 0) { rp[0] = 0; fil[0] = 0; }
}

// packed scatter: one 8B record per edge
__global__ __launch_bounds__(256) void scatter_both_kernel(
    const int* __restrict__ arows, const int* __restrict__ acols,
    const float* __restrict__ avals, int* __restrict__ filA,
    u64* __restrict__ epkA,
    const int* __restrict__ trows, const int* __restrict__ tcols,
    const float* __restrict__ tvals, int* __restrict__ filT,
    u64* __restrict__ epkT, int n)
{
    int e = blockIdx.x * 256 + threadIdx.x;
    if (e >= n) return;
    {
        int r = arows[e];
        int pos = atomicAdd(&filA[r], 1);
        epkA[pos] = ((u64)__float_as_uint(avals[e]) << 32) | (unsigned)acols[e];
    }
    if (epkT) {
        int r = trows[e];
        int pos = atomicAdd(&filT[r], 1);
        epkT[pos] = ((u64)__float_as_uint(tvals[e]) << 32) | (unsigned)tcols[e];
    }
}

// ---------------------------------------------------------------------------
// CSR gather SpMM, 4 edge-groups x 16 lanes x float4 per wave, one row/wave:
//   res[r] = scale * sum_e val*x[col] + add1[r] + add2[r]
//   if (out)  out[r]  = res
//   if (out2) out2[r] = res  (assign)  or  out2[r] += res
// ---------------------------------------------------------------------------
__global__ __launch_bounds__(256) void spmm_csr_kernel(
    const int* __restrict__ rowptr, const u64* __restrict__ epk,
    const float* __restrict__ xu, const float* __restrict__ xi,
    float scale, const float* __restrict__ add1, const float* __restrict__ add2,
    float* __restrict__ out, float* __restrict__ out2, int out2_assign, int n)
{
    int r = blockIdx.x * 4 + (threadIdx.x >> 6);
    if (r >= n) return;
    int lane = threadIdx.x & 63;
    int g = lane >> 4;          // edge group 0..3
    int l = lane & 15;          // feature chunk: floats 4l..4l+3

    int start = rowptr[r], end = rowptr[r + 1];
    float4 acc = {0.f, 0.f, 0.f, 0.f};
    for (int e = start + g; e < end; e += 4) {
        u64 pk = epk[e];
        int c   = (int)(unsigned)(pk & 0xffffffffu);
        float v = __uint_as_float((unsigned)(pk >> 32));
        const float* x = (c < USER) ? (xu + (size_t)c * LAT)
                                    : (xi + (size_t)(c - USER) * LAT);
        float4 xv = *(const float4*)(x + 4 * l);
        acc.x = fmaf(v, xv.x, acc.x);
        acc.y = fmaf(v, xv.y, acc.y);
        acc.z = fmaf(v, xv.z, acc.z);
        acc.w = fmaf(v, xv.w, acc.w);
    }
#pragma unroll
    for (int off = 16; off <= 32; off <<= 1) {
        acc.x += __shfl_xor(acc.x, off);
        acc.y += __shfl_xor(acc.y, off);
        acc.z += __shfl_xor(acc.z, off);
        acc.w += __shfl_xor(acc.w, off);
    }
    if (g == 0) {
        size_t idx = (size_t)r * LAT + 4 * l;
        float4 res = {scale * acc.x, scale * acc.y, scale * acc.z, scale * acc.w};
        if (add1) {
            float4 a = *(const float4*)(add1 + idx);
            res.x += a.x; res.y += a.y; res.z += a.z; res.w += a.w;
        }
        if (add2) {
            float4 a = *(const float4*)(add2 + idx);
            res.x += a.x; res.y += a.y; res.z += a.z; res.w += a.w;
        }
        if (out) *(float4*)(out + idx) = res;
        if (out2) {
            if (out2_assign) {
                *(float4*)(out2 + idx) = res;
            } else {
                float4 o = *(const float4*)(out2 + idx);
                o.x += res.x; o.y += res.y; o.z += res.z; o.w += res.w;
                *(float4*)(out2 + idx) = o;
            }
        }
    }
}

// ---------------------------------------------------------------------------
extern "C" void kernel_launch(void* const* d_in, const int* in_sizes, int n_in,
                              void* d_out, int out_size, void* d_ws, size_t ws_size,
                              hipStream_t stream)
{
    const float* u        = (const float*)d_in[0];
    const float* it       = (const float*)d_in[1];
    const float* text     = (const float*)d_in[2];
    const float* W        = (const float*)d_in[3];
    const float* b        = (const float*)d_in[4];
    const float* adj_vals = (const float*)d_in[5];
    const float* t_vals   = (const float*)d_in[6];
    const int*   adj_rows = (const int*)d_in[7];
    const int*   adj_cols = (const int*)d_in[8];
    const int*   t_rows   = (const int*)d_in[9];
    const int*   t_cols   = (const int*)d_in[10];
    const int E = in_sizes[5];

    float* out = (float*)d_out;

    // ---- workspace carve (fallback-needed arrays first, t-only last) ----
    char* p = (char*)d_ws;
    size_t used = 0;
    auto carve = [&](size_t bytes) {
        char* q = p + used;
        used += (bytes + 255) & ~(size_t)255;
        return q;
    };
    float* A    = (float*)carve((size_t)NNODE * LAT * 4);
    float* B    = (float*)carve((size_t)NNODE * LAT * 4);
    float* tf   = (float*)carve((size_t)ITEM * LAT * 4);
    int*   apA  = (int*)  carve((size_t)RP * 4);
    int*   filA = (int*)  carve((size_t)RP * 4);
    u64*   epkA = (u64*)  carve((size_t)E * 8);
    int*   bs   = (int*)  carve(8192);
    int*   cntA = (int*)  carve((size_t)RP * 4);   // cntA/cntT contiguous
    int*   cntT = (int*)  carve((size_t)RP * 4);
    int*   apT  = (int*)  carve((size_t)RP * 4);
    int*   filT = (int*)  carve((size_t)RP * 4);
    u64*   epkT = (u64*)  carve((size_t)E * 8);
    bool t_csr = (used <= ws_size);

    const int eblk  = (E + 255) / 256;
    const int nblk  = (NNODE + 255) / 256;
    const int nb    = (NNODE + 255) / 256;         // scan chunks (586)
    const int sblk  = (NNODE + 3) / 4;
    const int gblk  = (ITEM + 63) / 64;
    const dim3 y2a(nb,   t_csr ? 2 : 1);
    const dim3 y2b(nblk, t_csr ? 2 : 1);

    // ---- GEMM + normalize ----
    gemm_norm_kernel<<<gblk, 256, 0, stream>>>(text, W, b, tf, ITEM);

    // ---- build CSR(s) ----
    hipMemsetAsync(cntA, 0, (size_t)RP * 4 * (t_csr ? 2 : 1), stream);
    hist_both_kernel<<<eblk, 256, 0, stream>>>(adj_rows, cntA,
                                               t_rows, t_csr ? cntT : nullptr, E);
    scan1_kernel<<<y2a, 256, 0, stream>>>(cntA, apA, cntT, apT, bs, nb, NNODE);
    scan2_kernel<<<t_csr ? 2 : 1, 1024, 0, stream>>>(bs, nb);
    scan3_kernel<<<y2b, 256, 0, stream>>>(apA, filA, apT, filT, bs, nb, NNODE);
    scatter_both_kernel<<<eblk, 256, 0, stream>>>(
        adj_rows, adj_cols, adj_vals, filA, epkA,
        t_rows, t_cols, t_vals, filT, t_csr ? epkT : nullptr, E);

    // ---- A = 0.2 * spmm(t, concat(u, i)) ----
    if (t_csr) {
        spmm_csr_kernel<<<sblk, 256, 0, stream>>>(apT, epkT, u, it, 0.2f,
                                                  nullptr, nullptr, A, nullptr, 0, NNODE);
    } else {
        hipMemsetAsync(A, 0, (size_t)NNODE * LAT * 4, stream);
        spmm_atomic_kernel<<<(E + 3) / 4, 256, 0, stream>>>(
            t_rows, t_cols, t_vals, 0.2f, u, it, A, E);
    }

    // ---- B = e1 = spmm(adj, concat(u, tf)) ----
    spmm_csr_kernel<<<sblk, 256, 0, stream>>>(apA, epkA, u, tf, 1.0f,
                                              nullptr, nullptr, B, nullptr, 0, NNODE);
    // ---- A = embeds = e2 + A(lam*ta) + B(e1) ; out = embeds ----
    spmm_csr_kernel<<<sblk, 256, 0, stream>>>(apA, epkA, B, it, 1.0f,
                                              A, B, A, out, 1, NNODE);
    // ---- layer 1: B = spmm(adj, A) ; out += B ----
    spmm_csr_kernel<<<sblk, 256, 0, stream>>>(apA, epkA,
                                              A, A + (size_t)USER * LAT, 1.0f,
                                              nullptr, nullptr, B, out, 0, NNODE);
    // ---- layer 2: out += spmm(adj, B)  (dense result not materialized) ----
    spmm_csr_kernel<<<sblk, 256, 0, stream>>>(apA, epkA,
                                              B, B + (size_t)USER * LAT, 1.0f,
                                              nullptr, nullptr, nullptr, out, 0, NNODE);
}

// Round 5
// 1045.813 us; speedup vs baseline: 3.1384x; 1.0636x over previous
//
#include <hip/hip_runtime.h>

#define USER  100000
#define ITEM  50000
#define NNODE 150000
#define LAT   64
#define TXT   768
#define RP    150016          // padded rowptr/cnt length (>= NNODE+1)
#define NBUCK 8
#define BROWS (NNODE / NBUCK) // 18750 rows/bucket, window ~2.4MB fits XCD L2
#define SCHUNK 4096           // edges per block-chunk in scatter

typedef unsigned long long u64;

// ---------------------------------------------------------------------------
// Atomic-scatter SpMM fallback (t-adjacency only, if ws is too small for 2 CSRs)
// ---------------------------------------------------------------------------
__global__ __launch_bounds__(256) void spmm_atomic_kernel(
    const int* __restrict__ rows, const int* __restrict__ cols,
    const float* __restrict__ vals, float scale,
    const float* __restrict__ xu, const float* __restrict__ xi,
    float* __restrict__ out, int nedges)
{
    int e = blockIdx.x * 4 + (threadIdx.x >> 6);
    if (e >= nedges) return;
    int lane = threadIdx.x & 63;
    int r = rows[e];
    int c = cols[e];
    float v = vals[e] * scale;
    const float* x = (c < USER) ? (xu + (size_t)c * LAT)
                                : (xi + (size_t)(c - USER) * LAT);
    atomicAdd(&out[(size_t)r * LAT + lane], v * x[lane]);
}

// ---------------------------------------------------------------------------
// LDS-tiled GEMM + row L2-normalize:  tf = l2norm(text @ W + b)
// ---------------------------------------------------------------------------
__global__ __launch_bounds__(256) void gemm_norm_kernel(
    const float* __restrict__ text, const float* __restrict__ W,
    const float* __restrict__ b, float* __restrict__ tf, int nitems)
{
    __shared__ float As[32][68];     // [k][row], pad 68 => conflict-free b128
    __shared__ float Bs[32][64];     // [k][col]

    const int tid = threadIdx.x;
    const int tx  = tid & 15;
    const int ty  = tid >> 4;
    const int row0 = blockIdx.x * 64;

    float acc[4][4] = {};

    const int lrow = tid >> 3;             // 0..31
    const int lk4  = (tid & 7) * 4;        // 0,4,...,28

    for (int k0 = 0; k0 < TXT; k0 += 32) {
#pragma unroll
        for (int half = 0; half < 2; ++half) {
            int r = lrow + half * 32;
            int gr = row0 + r;
            if (gr >= nitems) gr = nitems - 1;
            float4 tv = *(const float4*)(text + (size_t)gr * TXT + k0 + lk4);
            As[lk4 + 0][r] = tv.x;
            As[lk4 + 1][r] = tv.y;
            As[lk4 + 2][r] = tv.z;
            As[lk4 + 3][r] = tv.w;
        }
        const float4* wf = (const float4*)(W + (size_t)k0 * LAT);
        ((float4*)Bs)[tid]       = wf[tid];
        ((float4*)Bs)[tid + 256] = wf[tid + 256];
        __syncthreads();

#pragma unroll
        for (int k = 0; k < 32; ++k) {
            float4 a4 = *(const float4*)&As[k][ty * 4];
            float4 b4 = *(const float4*)&Bs[k][tx * 4];
            float av[4] = {a4.x, a4.y, a4.z, a4.w};
            float bv[4] = {b4.x, b4.y, b4.z, b4.w};
#pragma unroll
            for (int i = 0; i < 4; ++i)
#pragma unroll
                for (int j = 0; j < 4; ++j)
                    acc[i][j] = fmaf(av[i], bv[j], acc[i][j]);
        }
        __syncthreads();
    }

    float4 b4 = *(const float4*)(b + tx * 4);
    float bv[4] = {b4.x, b4.y, b4.z, b4.w};
#pragma unroll
    for (int i = 0; i < 4; ++i) {
        float v[4];
        float ss = 0.f;
#pragma unroll
        for (int j = 0; j < 4; ++j) {
            v[j] = acc[i][j] + bv[j];
            ss = fmaf(v[j], v[j], ss);
        }
        ss += __shfl_xor(ss, 1);
        ss += __shfl_xor(ss, 2);
        ss += __shfl_xor(ss, 4);
        ss += __shfl_xor(ss, 8);
        float inv = 1.0f / fmaxf(sqrtf(ss), 1e-12f);
        int gr = row0 + ty * 4 + i;
        if (gr < nitems) {
            float4 o = {v[0] * inv, v[1] * inv, v[2] * inv, v[3] * inv};
            *(float4*)(tf + (size_t)gr * LAT + tx * 4) = o;
        }
    }
}

// ---------------------------------------------------------------------------
// CSR build: hist (both) -> scan -> bucketed scatter (per matrix)
// ---------------------------------------------------------------------------
__global__ __launch_bounds__(256) void hist_both_kernel(
    const int* __restrict__ arows, int* __restrict__ cntA,
    const int* __restrict__ trows, int* __restrict__ cntT, int n)
{
    int i = blockIdx.x * 256 + threadIdx.x;
    if (i >= n) return;
    atomicAdd(&cntA[arows[i]], 1);
    if (cntT) atomicAdd(&cntT[trows[i]], 1);
}

__global__ __launch_bounds__(256) void scan1_kernel(
    const int* __restrict__ cntA, int* __restrict__ rpA,
    const int* __restrict__ cntT, int* __restrict__ rpT,
    int* __restrict__ bsum, int nb, int n)
{
    const int* cnt = blockIdx.y ? cntT : cntA;
    int*       rp  = blockIdx.y ? rpT  : rpA;
    __shared__ int s[256];
    int i = blockIdx.x * 256 + threadIdx.x;
    int v = (i < n) ? cnt[i] : 0;
    s[threadIdx.x] = v;
    __syncthreads();
    for (int off = 1; off < 256; off <<= 1) {
        int t = (threadIdx.x >= off) ? s[threadIdx.x - off] : 0;
        __syncthreads();
        s[threadIdx.x] += t;
        __syncthreads();
    }
    if (i < n) rp[i + 1] = s[threadIdx.x];
    if (threadIdx.x == 255) bsum[blockIdx.y * nb + blockIdx.x] = s[255];
}

__global__ __launch_bounds__(1024) void scan2_kernel(int* __restrict__ bsum, int nb)
{
    int* bs = bsum + blockIdx.x * nb;
    __shared__ int s[1024];
    int t = threadIdx.x;
    int v = (t < nb) ? bs[t] : 0;
    s[t] = v;
    __syncthreads();
    for (int off = 1; off < 1024; off <<= 1) {
        int u = (t >= off) ? s[t - off] : 0;
        __syncthreads();
        s[t] += u;
        __syncthreads();
    }
    if (t < nb) bs[t] = s[t] - v;
}

__global__ __launch_bounds__(256) void scan3_kernel(
    int* __restrict__ rpA, int* __restrict__ filA,
    int* __restrict__ rpT, int* __restrict__ filT,
    const int* __restrict__ bsum, int nb, int n)
{
    int*       rp  = blockIdx.y ? rpT  : rpA;
    int*       fil = blockIdx.y ? filT : filA;
    const int* bs  = bsum + blockIdx.y * nb;
    int i = blockIdx.x * 256 + threadIdx.x;
    if (i < n) {
        int v = rp[i + 1] + bs[i >> 8];
        rp[i + 1] = v;
        if (i + 1 < n) fil[i + 1] = v;
    }
    if (i == 0) { rp[0] = 0; fil[0] = 0; }
}

// Bucketed packed scatter: bucket = blockIdx.x & 7 == XCD (round-robin
// dispatch), so each bucket's ~2.4MB record window stays dirty in ONE
// XCD's L2 until its 128B lines fill (16 records/line) -> ~1x writeback.
__global__ __launch_bounds__(256) void scatter_bucket_kernel(
    const int* __restrict__ rows, const int* __restrict__ cols,
    const float* __restrict__ vals, int* __restrict__ fil,
    u64* __restrict__ epk, int n)
{
    const int bucket = blockIdx.x & (NBUCK - 1);
    const int lo = bucket * BROWS;
    const int hi = lo + BROWS;
    const int base = (blockIdx.x >> 3) * SCHUNK;
    const int end = min(n, base + SCHUNK);
    for (int e = base + threadIdx.x; e < end; e += 256) {
        int r = rows[e];
        if (r >= lo && r < hi) {
            int pos = atomicAdd(&fil[r], 1);
            epk[pos] = ((u64)__float_as_uint(vals[e]) << 32) | (unsigned)cols[e];
        }
    }
}

// ---------------------------------------------------------------------------
// CSR gather SpMM, 4 edge-groups x 16 lanes x float4 per wave, one row/wave:
//   res[r] = scale * sum_e val*x[col] + add1[r] + add2[r]
//   if (out)  out[r]  = res
//   if (out2) out2[r] = res (assign) or out2[r] += res
// ---------------------------------------------------------------------------
__global__ __launch_bounds__(256) void spmm_csr_kernel(
    const int* __restrict__ rowptr, const u64* __restrict__ epk,
    const float* __restrict__ xu, const float* __restrict__ xi,
    float scale, const float* __restrict__ add1, const float* __restrict__ add2,
    float* __restrict__ out, float* __restrict__ out2, int out2_assign, int n)
{
    int r = blockIdx.x * 4 + (threadIdx.x >> 6);
    if (r >= n) return;
    int lane = threadIdx.x & 63;
    int g = lane >> 4;
    int l = lane & 15;

    int start = rowptr[r], end = rowptr[r + 1];
    float4 acc = {0.f, 0.f, 0.f, 0.f};
    for (int e = start + g; e < end; e += 4) {
        u64 pk = epk[e];
        int c   = (int)(unsigned)(pk & 0xffffffffu);
        float v = __uint_as_float((unsigned)(pk >> 32));
        const float* x = (c < USER) ? (xu + (size_t)c * LAT)
                                    : (xi + (size_t)(c - USER) * LAT);
        float4 xv = *(const float4*)(x + 4 * l);
        acc.x = fmaf(v, xv.x, acc.x);
        acc.y = fmaf(v, xv.y, acc.y);
        acc.z = fmaf(v, xv.z, acc.z);
        acc.w = fmaf(v, xv.w, acc.w);
    }
#pragma unroll
    for (int off = 16; off <= 32; off <<= 1) {
        acc.x += __shfl_xor(acc.x, off);
        acc.y += __shfl_xor(acc.y, off);
        acc.z += __shfl_xor(acc.z, off);
        acc.w += __shfl_xor(acc.w, off);
    }
    if (g == 0) {
        size_t idx = (size_t)r * LAT + 4 * l;
        float4 res = {scale * acc.x, scale * acc.y, scale * acc.z, scale * acc.w};
        if (add1) {
            float4 a = *(const float4*)(add1 + idx);
            res.x += a.x; res.y += a.y; res.z += a.z; res.w += a.w;
        }
        if (add2) {
            float4 a = *(const float4*)(add2 + idx);
            res.x += a.x; res.y += a.y; res.z += a.z; res.w += a.w;
        }
        if (out) *(float4*)(out + idx) = res;
        if (out2) {
            if (out2_assign) {
                *(float4*)(out2 + idx) = res;
            } else {
                float4 o = *(const float4*)(out2 + idx);
                o.x += res.x; o.y += res.y; o.z += res.z; o.w += res.w;
                *(float4*)(out2 + idx) = o;
            }
        }
    }
}

// ---------------------------------------------------------------------------
extern "C" void kernel_launch(void* const* d_in, const int* in_sizes, int n_in,
                              void* d_out, int out_size, void* d_ws, size_t ws_size,
                              hipStream_t stream)
{
    const float* u        = (const float*)d_in[0];
    const float* it       = (const float*)d_in[1];
    const float* text     = (const float*)d_in[2];
    const float* W        = (const float*)d_in[3];
    const float* b        = (const float*)d_in[4];
    const float* adj_vals = (const float*)d_in[5];
    const float* t_vals   = (const float*)d_in[6];
    const int*   adj_rows = (const int*)d_in[7];
    const int*   adj_cols = (const int*)d_in[8];
    const int*   t_rows   = (const int*)d_in[9];
    const int*   t_cols   = (const int*)d_in[10];
    const int E = in_sizes[5];

    float* out = (float*)d_out;

    // ---- workspace carve (fallback-needed arrays first, t-only last) ----
    char* p = (char*)d_ws;
    size_t used = 0;
    auto carve = [&](size_t bytes) {
        char* q = p + used;
        used += (bytes + 255) & ~(size_t)255;
        return q;
    };
    float* A    = (float*)carve((size_t)NNODE * LAT * 4);
    float* B    = (float*)carve((size_t)NNODE * LAT * 4);
    float* tf   = (float*)carve((size_t)ITEM * LAT * 4);
    int*   apA  = (int*)  carve((size_t)RP * 4);
    int*   filA = (int*)  carve((size_t)RP * 4);
    u64*   epkA = (u64*)  carve((size_t)E * 8);
    int*   bs   = (int*)  carve(8192);
    int*   cntA = (int*)  carve((size_t)RP * 4);   // cntA/cntT contiguous
    int*   cntT = (int*)  carve((size_t)RP * 4);
    int*   apT  = (int*)  carve((size_t)RP * 4);
    int*   filT = (int*)  carve((size_t)RP * 4);
    u64*   epkT = (u64*)  carve((size_t)E * 8);
    bool t_csr = (used <= ws_size);

    const int eblk  = (E + 255) / 256;
    const int nblk  = (NNODE + 255) / 256;
    const int nb    = (NNODE + 255) / 256;         // scan chunks (586)
    const int sblk  = (NNODE + 3) / 4;
    const int gblk  = (ITEM + 63) / 64;
    const int scblk = ((E + SCHUNK - 1) / SCHUNK) * NBUCK;
    const dim3 y2a(nb,   t_csr ? 2 : 1);
    const dim3 y2b(nblk, t_csr ? 2 : 1);

    // ---- GEMM + normalize ----
    gemm_norm_kernel<<<gblk, 256, 0, stream>>>(text, W, b, tf, ITEM);

    // ---- build CSR(s) ----
    hipMemsetAsync(cntA, 0, (size_t)RP * 4 * (t_csr ? 2 : 1), stream);
    hist_both_kernel<<<eblk, 256, 0, stream>>>(adj_rows, cntA,
                                               t_rows, t_csr ? cntT : nullptr, E);
    scan1_kernel<<<y2a, 256, 0, stream>>>(cntA, apA, cntT, apT, bs, nb, NNODE);
    scan2_kernel<<<t_csr ? 2 : 1, 1024, 0, stream>>>(bs, nb);
    scan3_kernel<<<y2b, 256, 0, stream>>>(apA, filA, apT, filT, bs, nb, NNODE);
    scatter_bucket_kernel<<<scblk, 256, 0, stream>>>(
        adj_rows, adj_cols, adj_vals, filA, epkA, E);
    if (t_csr)
        scatter_bucket_kernel<<<scblk, 256, 0, stream>>>(
            t_rows, t_cols, t_vals, filT, epkT, E);

    // ---- A = 0.2 * spmm(t, concat(u, i)) ----
    if (t_csr) {
        spmm_csr_kernel<<<sblk, 256, 0, stream>>>(apT, epkT, u, it, 0.2f,
                                                  nullptr, nullptr, A, nullptr, 0, NNODE);
    } else {
        hipMemsetAsync(A, 0, (size_t)NNODE * LAT * 4, stream);
        spmm_atomic_kernel<<<(E + 3) / 4, 256, 0, stream>>>(
            t_rows, t_cols, t_vals, 0.2f, u, it, A, E);
    }

    // ---- B = e1 = spmm(adj, concat(u, tf)) ----
    spmm_csr_kernel<<<sblk, 256, 0, stream>>>(apA, epkA, u, tf, 1.0f,
                                              nullptr, nullptr, B, nullptr, 0, NNODE);
    // ---- A = embeds = e2 + A(lam*ta) + B(e1) ; out = embeds ----
    spmm_csr_kernel<<<sblk, 256, 0, stream>>>(apA, epkA, B, it, 1.0f,
                                              A, B, A, out, 1, NNODE);
    // ---- layer 1: B = spmm(adj, A) ; out += B ----
    spmm_csr_kernel<<<sblk, 256, 0, stream>>>(apA, epkA,
                                              A, A + (size_t)USER * LAT, 1.0f,
                                              nullptr, nullptr, B, out, 0, NNODE);
    // ---- layer 2: out += spmm(adj, B)  (dense result not materialized) ----
    spmm_csr_kernel<<<sblk, 256, 0, stream>>>(apA, epkA,
                                              B, B + (size_t)USER * LAT, 1.0f,
                                              nullptr, nullptr, nullptr, out, 0, NNODE);
}

// Round 6
// 903.226 us; speedup vs baseline: 3.6338x; 1.1579x over previous
//
#include <hip/hip_runtime.h>

#define USER  100000
#define ITEM  50000
#define NNODE 150000
#define LAT   64
#define TXT   768
#define RP    150016          // padded rowptr/cnt length (>= NNODE+1)
#define NBUCK 8
#define BROWS (NNODE / NBUCK) // 18750 rows/bucket
#define SCHUNK 4096           // edges per block-chunk in scatter
#define CAP   64              // padded-CSR row capacity (max degree ~40)

typedef unsigned long long u64;

// ---------------------------------------------------------------------------
// Atomic-scatter SpMM fallback (t-adjacency only, smallest-ws path)
// ---------------------------------------------------------------------------
__global__ __launch_bounds__(256) void spmm_atomic_kernel(
    const int* __restrict__ rows, const int* __restrict__ cols,
    const float* __restrict__ vals, float scale,
    const float* __restrict__ xu, const float* __restrict__ xi,
    float* __restrict__ out, int nedges)
{
    int e = blockIdx.x * 4 + (threadIdx.x >> 6);
    if (e >= nedges) return;
    int lane = threadIdx.x & 63;
    int r = rows[e];
    int c = cols[e];
    float v = vals[e] * scale;
    const float* x = (c < USER) ? (xu + (size_t)c * LAT)
                                : (xi + (size_t)(c - USER) * LAT);
    atomicAdd(&out[(size_t)r * LAT + lane], v * x[lane]);
}

// ---------------------------------------------------------------------------
// LDS-tiled GEMM + row L2-normalize:  tf = l2norm(text @ W + b)
// ---------------------------------------------------------------------------
__global__ __launch_bounds__(256) void gemm_norm_kernel(
    const float* __restrict__ text, const float* __restrict__ W,
    const float* __restrict__ b, float* __restrict__ tf, int nitems)
{
    __shared__ float As[32][68];     // [k][row], pad 68 => conflict-free b128
    __shared__ float Bs[32][64];     // [k][col]

    const int tid = threadIdx.x;
    const int tx  = tid & 15;
    const int ty  = tid >> 4;
    const int row0 = blockIdx.x * 64;

    float acc[4][4] = {};

    const int lrow = tid >> 3;             // 0..31
    const int lk4  = (tid & 7) * 4;        // 0,4,...,28

    for (int k0 = 0; k0 < TXT; k0 += 32) {
#pragma unroll
        for (int half = 0; half < 2; ++half) {
            int r = lrow + half * 32;
            int gr = row0 + r;
            if (gr >= nitems) gr = nitems - 1;
            float4 tv = *(const float4*)(text + (size_t)gr * TXT + k0 + lk4);
            As[lk4 + 0][r] = tv.x;
            As[lk4 + 1][r] = tv.y;
            As[lk4 + 2][r] = tv.z;
            As[lk4 + 3][r] = tv.w;
        }
        const float4* wf = (const float4*)(W + (size_t)k0 * LAT);
        ((float4*)Bs)[tid]       = wf[tid];
        ((float4*)Bs)[tid + 256] = wf[tid + 256];
        __syncthreads();

#pragma unroll
        for (int k = 0; k < 32; ++k) {
            float4 a4 = *(const float4*)&As[k][ty * 4];
            float4 b4 = *(const float4*)&Bs[k][tx * 4];
            float av[4] = {a4.x, a4.y, a4.z, a4.w};
            float bv[4] = {b4.x, b4.y, b4.z, b4.w};
#pragma unroll
            for (int i = 0; i < 4; ++i)
#pragma unroll
                for (int j = 0; j < 4; ++j)
                    acc[i][j] = fmaf(av[i], bv[j], acc[i][j]);
        }
        __syncthreads();
    }

    float4 b4 = *(const float4*)(b + tx * 4);
    float bv[4] = {b4.x, b4.y, b4.z, b4.w};
#pragma unroll
    for (int i = 0; i < 4; ++i) {
        float v[4];
        float ss = 0.f;
#pragma unroll
        for (int j = 0; j < 4; ++j) {
            v[j] = acc[i][j] + bv[j];
            ss = fmaf(v[j], v[j], ss);
        }
        ss += __shfl_xor(ss, 1);
        ss += __shfl_xor(ss, 2);
        ss += __shfl_xor(ss, 4);
        ss += __shfl_xor(ss, 8);
        float inv = 1.0f / fmaxf(sqrtf(ss), 1e-12f);
        int gr = row0 + ty * 4 + i;
        if (gr < nitems) {
            float4 o = {v[0] * inv, v[1] * inv, v[2] * inv, v[3] * inv};
            *(float4*)(tf + (size_t)gr * LAT + tx * 4) = o;
        }
    }
}

// ---------------------------------------------------------------------------
// Padded-CSR scatter: no histogram/scan needed. Row r's records fill slots
// epk[r*CAP .. r*CAP+deg). Bucketed (bucket = blockIdx.x&7 == XCD via
// round-robin dispatch) so each bucket's active dirty window (~2.4MB: only
// the leading line(s) of each row get written) stays in ONE XCD's L2.
// ---------------------------------------------------------------------------
__global__ __launch_bounds__(256) void scatter_pad_kernel(
    const int* __restrict__ rows, const int* __restrict__ cols,
    const float* __restrict__ vals, int* __restrict__ fil,
    u64* __restrict__ epk, int n)
{
    const int bucket = blockIdx.x & (NBUCK - 1);
    const int lo = bucket * BROWS;
    const int hi = lo + BROWS;
    const int base = (blockIdx.x >> 3) * SCHUNK;
    const int end = min(n, base + SCHUNK);
    for (int e = base + threadIdx.x; e < end; e += 256) {
        int r = rows[e];
        if (r >= lo && r < hi) {
            int pos = atomicAdd(&fil[r], 1);
            if (pos < CAP)   // mathematically never exceeded; memory-safety
                epk[((size_t)r << 6) + pos] =
                    ((u64)__float_as_uint(vals[e]) << 32) | (unsigned)cols[e];
        }
    }
}

// ---------------------------------------------------------------------------
// Exact-CSR build machinery (fallback when ws too small for padded layout)
// ---------------------------------------------------------------------------
__global__ __launch_bounds__(256) void hist_both_kernel(
    const int* __restrict__ arows, int* __restrict__ cntA,
    const int* __restrict__ trows, int* __restrict__ cntT, int n)
{
    int i = blockIdx.x * 256 + threadIdx.x;
    if (i >= n) return;
    atomicAdd(&cntA[arows[i]], 1);
    if (cntT) atomicAdd(&cntT[trows[i]], 1);
}

__global__ __launch_bounds__(256) void scan1_kernel(
    const int* __restrict__ cntA, int* __restrict__ rpA,
    const int* __restrict__ cntT, int* __restrict__ rpT,
    int* __restrict__ bsum, int nb, int n)
{
    const int* cnt = blockIdx.y ? cntT : cntA;
    int*       rp  = blockIdx.y ? rpT  : rpA;
    __shared__ int s[256];
    int i = blockIdx.x * 256 + threadIdx.x;
    int v = (i < n) ? cnt[i] : 0;
    s[threadIdx.x] = v;
    __syncthreads();
    for (int off = 1; off < 256; off <<= 1) {
        int t = (threadIdx.x >= off) ? s[threadIdx.x - off] : 0;
        __syncthreads();
        s[threadIdx.x] += t;
        __syncthreads();
    }
    if (i < n) rp[i + 1] = s[threadIdx.x];
    if (threadIdx.x == 255) bsum[blockIdx.y * nb + blockIdx.x] = s[255];
}

__global__ __launch_bounds__(1024) void scan2_kernel(int* __restrict__ bsum, int nb)
{
    int* bs = bsum + blockIdx.x * nb;
    __shared__ int s[1024];
    int t = threadIdx.x;
    int v = (t < nb) ? bs[t] : 0;
    s[t] = v;
    __syncthreads();
    for (int off = 1; off < 1024; off <<= 1) {
        int u = (t >= off) ? s[t - off] : 0;
        __syncthreads();
        s[t] += u;
        __syncthreads();
    }
    if (t < nb) bs[t] = s[t] - v;
}

__global__ __launch_bounds__(256) void scan3_kernel(
    int* __restrict__ rpA, int* __restrict__ filA,
    int* __restrict__ rpT, int* __restrict__ filT,
    const int* __restrict__ bsum, int nb, int n)
{
    int*       rp  = blockIdx.y ? rpT  : rpA;
    int*       fil = blockIdx.y ? filT : filA;
    const int* bs  = bsum + blockIdx.y * nb;
    int i = blockIdx.x * 256 + threadIdx.x;
    if (i < n) {
        int v = rp[i + 1] + bs[i >> 8];
        rp[i + 1] = v;
        if (i + 1 < n) fil[i + 1] = v;
    }
    if (i == 0) { rp[0] = 0; fil[0] = 0; }
}

__global__ __launch_bounds__(256) void scatter_bucket_kernel(
    const int* __restrict__ rows, const int* __restrict__ cols,
    const float* __restrict__ vals, int* __restrict__ fil,
    u64* __restrict__ epk, int n)
{
    const int bucket = blockIdx.x & (NBUCK - 1);
    const int lo = bucket * BROWS;
    const int hi = lo + BROWS;
    const int base = (blockIdx.x >> 3) * SCHUNK;
    const int end = min(n, base + SCHUNK);
    for (int e = base + threadIdx.x; e < end; e += 256) {
        int r = rows[e];
        if (r >= lo && r < hi) {
            int pos = atomicAdd(&fil[r], 1);
            epk[pos] = ((u64)__float_as_uint(vals[e]) << 32) | (unsigned)cols[e];
        }
    }
}

// ---------------------------------------------------------------------------
// Gather SpMM (exact-CSR via rowptr, or padded via cnt), one row/wave,
// 4 edge-groups x 16 lanes x float4:
//   res[r] = scale * sum_e val*x[col] + add1[r] + add2[r]
//   if (out)  out[r]  = res
//   if (out2) out2[r] = res (assign) or out2[r] += res
// ---------------------------------------------------------------------------
__global__ __launch_bounds__(256) void spmm_kernel(
    const int* __restrict__ rowptr, const int* __restrict__ cnt,
    const u64* __restrict__ epk,
    const float* __restrict__ xu, const float* __restrict__ xi,
    float scale, const float* __restrict__ add1, const float* __restrict__ add2,
    float* __restrict__ out, float* __restrict__ out2, int out2_assign, int n)
{
    int r = blockIdx.x * 4 + (threadIdx.x >> 6);
    if (r >= n) return;
    int lane = threadIdx.x & 63;
    int g = lane >> 4;
    int l = lane & 15;

    size_t start, end;
    if (cnt) {
        start = (size_t)r << 6;
        end   = start + min(cnt[r], CAP);
    } else {
        start = rowptr[r];
        end   = rowptr[r + 1];
    }
    float4 acc = {0.f, 0.f, 0.f, 0.f};
    for (size_t e = start + g; e < end; e += 4) {
        u64 pk = epk[e];
        int c   = (int)(unsigned)(pk & 0xffffffffu);
        float v = __uint_as_float((unsigned)(pk >> 32));
        const float* x = (c < USER) ? (xu + (size_t)c * LAT)
                                    : (xi + (size_t)(c - USER) * LAT);
        float4 xv = *(const float4*)(x + 4 * l);
        acc.x = fmaf(v, xv.x, acc.x);
        acc.y = fmaf(v, xv.y, acc.y);
        acc.z = fmaf(v, xv.z, acc.z);
        acc.w = fmaf(v, xv.w, acc.w);
    }
#pragma unroll
    for (int off = 16; off <= 32; off <<= 1) {
        acc.x += __shfl_xor(acc.x, off);
        acc.y += __shfl_xor(acc.y, off);
        acc.z += __shfl_xor(acc.z, off);
        acc.w += __shfl_xor(acc.w, off);
    }
    if (g == 0) {
        size_t idx = (size_t)r * LAT + 4 * l;
        float4 res = {scale * acc.x, scale * acc.y, scale * acc.z, scale * acc.w};
        if (add1) {
            float4 a = *(const float4*)(add1 + idx);
            res.x += a.x; res.y += a.y; res.z += a.z; res.w += a.w;
        }
        if (add2) {
            float4 a = *(const float4*)(add2 + idx);
            res.x += a.x; res.y += a.y; res.z += a.z; res.w += a.w;
        }
        if (out) *(float4*)(out + idx) = res;
        if (out2) {
            if (out2_assign) {
                *(float4*)(out2 + idx) = res;
            } else {
                float4 o = *(const float4*)(out2 + idx);
                o.x += res.x; o.y += res.y; o.z += res.z; o.w += res.w;
                *(float4*)(out2 + idx) = o;
            }
        }
    }
}

// ---------------------------------------------------------------------------
extern "C" void kernel_launch(void* const* d_in, const int* in_sizes, int n_in,
                              void* d_out, int out_size, void* d_ws, size_t ws_size,
                              hipStream_t stream)
{
    const float* u        = (const float*)d_in[0];
    const float* it       = (const float*)d_in[1];
    const float* text     = (const float*)d_in[2];
    const float* W        = (const float*)d_in[3];
    const float* b        = (const float*)d_in[4];
    const float* adj_vals = (const float*)d_in[5];
    const float* t_vals   = (const float*)d_in[6];
    const int*   adj_rows = (const int*)d_in[7];
    const int*   adj_cols = (const int*)d_in[8];
    const int*   t_rows   = (const int*)d_in[9];
    const int*   t_cols   = (const int*)d_in[10];
    const int E = in_sizes[5];

    float* out = (float*)d_out;

    const int eblk  = (E + 255) / 256;
    const int nblk  = (NNODE + 255) / 256;
    const int nb    = (NNODE + 255) / 256;
    const int sblk  = (NNODE + 3) / 4;
    const int gblk  = (ITEM + 63) / 64;
    const int scblk = ((E + SCHUNK - 1) / SCHUNK) * NBUCK;

    // ---- workspace carve: shared dense buffers first ----
    char* p = (char*)d_ws;
    size_t used = 0;
    auto carve = [&](size_t bytes) {
        char* q = p + used;
        used += (bytes + 255) & ~(size_t)255;
        return q;
    };
    float* A    = (float*)carve((size_t)NNODE * LAT * 4);
    float* B    = (float*)carve((size_t)NNODE * LAT * 4);
    float* tf   = (float*)carve((size_t)ITEM * LAT * 4);
    size_t dense_used = used;

    // padded layout
    int*   filA = (int*)  carve((size_t)RP * 4);
    int*   filT = (int*)  carve((size_t)RP * 4);
    u64*   epkA = (u64*)  carve((size_t)NNODE * CAP * 8);
    u64*   epkT = (u64*)  carve((size_t)NNODE * CAP * 8);
    bool padded = (used <= ws_size);

    // ---- GEMM + normalize (independent of CSR build) ----
    gemm_norm_kernel<<<gblk, 256, 0, stream>>>(text, W, b, tf, ITEM);

    if (padded) {
        // ---- padded-CSR build: zero fil, scatter (no hist/scan) ----
        hipMemsetAsync(filA, 0, (size_t)RP * 4 * 2, stream);   // filA+filT contiguous
        scatter_pad_kernel<<<scblk, 256, 0, stream>>>(
            adj_rows, adj_cols, adj_vals, filA, epkA, E);
        scatter_pad_kernel<<<scblk, 256, 0, stream>>>(
            t_rows, t_cols, t_vals, filT, epkT, E);

        // ---- A = 0.2 * spmm(t, concat(u, i)) ----
        spmm_kernel<<<sblk, 256, 0, stream>>>(nullptr, filT, epkT, u, it, 0.2f,
                                              nullptr, nullptr, A, nullptr, 0, NNODE);
        // ---- B = e1 = spmm(adj, concat(u, tf)) ----
        spmm_kernel<<<sblk, 256, 0, stream>>>(nullptr, filA, epkA, u, tf, 1.0f,
                                              nullptr, nullptr, B, nullptr, 0, NNODE);
        // ---- A = embeds = e2 + A(lam*ta) + B(e1) ; out = embeds ----
        spmm_kernel<<<sblk, 256, 0, stream>>>(nullptr, filA, epkA, B, it, 1.0f,
                                              A, B, A, out, 1, NNODE);
        // ---- layer 1: B = spmm(adj, A) ; out += B ----
        spmm_kernel<<<sblk, 256, 0, stream>>>(nullptr, filA, epkA,
                                              A, A + (size_t)USER * LAT, 1.0f,
                                              nullptr, nullptr, B, out, 0, NNODE);
        // ---- layer 2: out += spmm(adj, B) ----
        spmm_kernel<<<sblk, 256, 0, stream>>>(nullptr, filA, epkA,
                                              B, B + (size_t)USER * LAT, 1.0f,
                                              nullptr, nullptr, nullptr, out, 0, NNODE);
        return;
    }

    // =======================================================================
    // Fallback: exact-CSR path (hist -> scan -> bucketed scatter)
    // =======================================================================
    used = dense_used;
    int*   apA  = (int*)  carve((size_t)RP * 4);
    int*   filA2= (int*)  carve((size_t)RP * 4);
    u64*   ecA  = (u64*)  carve((size_t)E * 8);
    int*   bs   = (int*)  carve(8192);
    int*   cntA = (int*)  carve((size_t)RP * 4);   // cntA/cntT contiguous
    int*   cntT = (int*)  carve((size_t)RP * 4);
    int*   apT  = (int*)  carve((size_t)RP * 4);
    int*   filT2= (int*)  carve((size_t)RP * 4);
    u64*   ecT  = (u64*)  carve((size_t)E * 8);
    bool t_csr = (used <= ws_size);

    const dim3 y2a(nb,   t_csr ? 2 : 1);
    const dim3 y2b(nblk, t_csr ? 2 : 1);

    hipMemsetAsync(cntA, 0, (size_t)RP * 4 * (t_csr ? 2 : 1), stream);
    hist_both_kernel<<<eblk, 256, 0, stream>>>(adj_rows, cntA,
                                               t_rows, t_csr ? cntT : nullptr, E);
    scan1_kernel<<<y2a, 256, 0, stream>>>(cntA, apA, cntT, apT, bs, nb, NNODE);
    scan2_kernel<<<t_csr ? 2 : 1, 1024, 0, stream>>>(bs, nb);
    scan3_kernel<<<y2b, 256, 0, stream>>>(apA, filA2, apT, filT2, bs, nb, NNODE);
    scatter_bucket_kernel<<<scblk, 256, 0, stream>>>(
        adj_rows, adj_cols, adj_vals, filA2, ecA, E);
    if (t_csr)
        scatter_bucket_kernel<<<scblk, 256, 0, stream>>>(
            t_rows, t_cols, t_vals, filT2, ecT, E);

    if (t_csr) {
        spmm_kernel<<<sblk, 256, 0, stream>>>(apT, nullptr, ecT, u, it, 0.2f,
                                              nullptr, nullptr, A, nullptr, 0, NNODE);
    } else {
        hipMemsetAsync(A, 0, (size_t)NNODE * LAT * 4, stream);
        spmm_atomic_kernel<<<(E + 3) / 4, 256, 0, stream>>>(
            t_rows, t_cols, t_vals, 0.2f, u, it, A, E);
    }
    spmm_kernel<<<sblk, 256, 0, stream>>>(apA, nullptr, ecA, u, tf, 1.0f,
                                          nullptr, nullptr, B, nullptr, 0, NNODE);
    spmm_kernel<<<sblk, 256, 0, stream>>>(apA, nullptr, ecA, B, it, 1.0f,
                                          A, B, A, out, 1, NNODE);
    spmm_kernel<<<sblk, 256, 0, stream>>>(apA, nullptr, ecA,
                                          A, A + (size_t)USER * LAT, 1.0f,
                                          nullptr, nullptr, B, out, 0, NNODE);
    spmm_kernel<<<sblk, 256, 0, stream>>>(apA, nullptr, ecA,
                                          B, B + (size_t)USER * LAT, 1.0f,
                                          nullptr, nullptr, nullptr, out, 0, NNODE);
}